// Round 6
// baseline (513.419 us; speedup 1.0000x reference)
//
#include <hip/hip_runtime.h>
#include <stdint.h>

// ---------- types ----------
typedef __bf16 bf16_8 __attribute__((ext_vector_type(8)));
typedef __bf16 bf16_4 __attribute__((ext_vector_type(4)));
typedef float  f32x4  __attribute__((ext_vector_type(4)));

#define B_  1
#define S_  2048
#define D_  4096
#define H_  32
#define KV_ 8
#define HD_ 128

__device__ inline void gload_lds16(const void* g, void* l) {
  __builtin_amdgcn_global_load_lds((const __attribute__((address_space(1))) void*)g,
                                   (__attribute__((address_space(3))) void*)l, 16, 0, 0);
}

// ---------- fused fp32 -> bf16 convert (all 5 tensors; dst contiguous in ws) ----------
__global__ __launch_bounds__(256) void cvt_all(const float* __restrict__ x,
                                               const float* __restrict__ wq,
                                               const float* __restrict__ wk,
                                               const float* __restrict__ wv,
                                               const float* __restrict__ wo,
                                               __bf16* __restrict__ dst) {
  int i = blockIdx.x * 256 + threadIdx.x;  // float4-chunk index, total 12,582,912
  const float* s;
  int j = i;
  if (j < 2097152) s = x;
  else if ((j -= 2097152) < 4194304) s = wq;
  else if ((j -= 4194304) < 1048576) s = wk;
  else if ((j -= 1048576) < 1048576) s = wv;
  else { j -= 1048576; s = wo; }
  float4 v = ((const float4*)s)[j];
  bf16_4 o = { (__bf16)v.x, (__bf16)v.y, (__bf16)v.z, (__bf16)v.w };
  ((bf16_4*)dst)[i] = o;
}

// ---------- RoPE (in-place on bf16 Q and K) ----------
__global__ __launch_bounds__(256) void rope_k(__bf16* __restrict__ Qb, __bf16* __restrict__ Kb,
                                              const float* __restrict__ cosT,
                                              const float* __restrict__ sinT) {
  int t = blockIdx.x * 256 + threadIdx.x;
  const int NQ = S_ * (D_ / 8);
  __bf16* p;
  int row, cl8;
  if (t < NQ) { row = t >> 9; cl8 = t & 511; p = Qb + (size_t)row * D_ + cl8 * 8; }
  else        { int u = t - NQ; row = u >> 7; cl8 = u & 127; p = Kb + (size_t)row * 1024 + cl8 * 8; }
  bf16_8 v = *(bf16_8*)p;
  int fi0 = ((cl8 * 8) & 127) >> 1;
  float4 c4 = *(const float4*)&cosT[row * 64 + fi0];
  float4 s4 = *(const float4*)&sinT[row * 64 + fi0];
  float cc[4] = {c4.x, c4.y, c4.z, c4.w};
  float ss[4] = {s4.x, s4.y, s4.z, s4.w};
  bf16_8 o;
#pragma unroll
  for (int j = 0; j < 4; ++j) {
    float xr = (float)v[2 * j], xi = (float)v[2 * j + 1];
    o[2 * j]     = (__bf16)(xr * cc[j] - xi * ss[j]);
    o[2 * j + 1] = (__bf16)(xr * ss[j] + xi * cc[j]);
  }
  *(bf16_8*)p = o;
}

// ---------- fused QKV GEMM (m97-style 128x128 tile, BK=32) ----------
__global__ __launch_bounds__(256) void gemm_qkv(const __bf16* __restrict__ xb,
                                                const __bf16* __restrict__ wqb,
                                                const __bf16* __restrict__ wkb,
                                                const __bf16* __restrict__ wvb,
                                                __bf16* __restrict__ Qb,
                                                __bf16* __restrict__ Kb,
                                                __bf16* __restrict__ Vt) {
  __shared__ __bf16 As[128 * 32];
  __shared__ __bf16 Bs[128 * 32];
  const int nb = blockIdx.x, mb = blockIdx.y;
  const __bf16* W; int wrow0;
  if (nb < 32)      { W = wqb; wrow0 = nb * 128; }
  else if (nb < 40) { W = wkb; wrow0 = (nb - 32) * 128; }
  else              { W = wvb; wrow0 = (nb - 40) * 128; }
  const int tid = threadIdx.x, lane = tid & 63, wv = tid >> 6;
  const int wm = wv >> 1, wn = wv & 1;
  const int srow = lane >> 2, scol = (lane & 3) * 8;

  const __bf16* Ag0 = xb + (size_t)(mb * 128 + 2 * wv * 16 + srow) * D_ + scol;
  const __bf16* Bg0 = W  + (size_t)(wrow0 + 2 * wv * 16 + srow) * D_ + scol;
  __bf16* Al = As + 2 * wv * 512;
  __bf16* Bl = Bs + 2 * wv * 512;

  const f32x4 zv = {0.f, 0.f, 0.f, 0.f};
  f32x4 acc[4][4];
#pragma unroll
  for (int i = 0; i < 4; ++i)
#pragma unroll
    for (int j = 0; j < 4; ++j) acc[i][j] = zv;

  for (int k0 = 0; k0 < D_; k0 += 32) {
    gload_lds16(Ag0 + k0, Al);
    gload_lds16(Ag0 + (size_t)16 * D_ + k0, Al + 512);
    gload_lds16(Bg0 + k0, Bl);
    gload_lds16(Bg0 + (size_t)16 * D_ + k0, Bl + 512);
    __syncthreads();
    bf16_8 af[4], bfr[4];
#pragma unroll
    for (int i = 0; i < 4; ++i)
      af[i] = *(const bf16_8*)&As[(wm * 64 + i * 16 + (lane & 15)) * 32 + (lane >> 4) * 8];
#pragma unroll
    for (int j = 0; j < 4; ++j)
      bfr[j] = *(const bf16_8*)&Bs[(wn * 64 + j * 16 + (lane & 15)) * 32 + (lane >> 4) * 8];
#pragma unroll
    for (int i = 0; i < 4; ++i)
#pragma unroll
      for (int j = 0; j < 4; ++j)
        acc[i][j] = __builtin_amdgcn_mfma_f32_16x16x32_bf16(af[i], bfr[j], acc[i][j], 0, 0, 0);
    __syncthreads();
  }

#pragma unroll
  for (int i = 0; i < 4; ++i) {
    int row0 = mb * 128 + wm * 64 + i * 16 + (lane >> 4) * 4;
#pragma unroll
    for (int j = 0; j < 4; ++j) {
      int cl = wn * 64 + j * 16 + (lane & 15);
      if (nb < 32) {
        int colg = nb * 128 + cl;
#pragma unroll
        for (int r = 0; r < 4; ++r)
          Qb[(size_t)(row0 + r) * D_ + colg] = (__bf16)acc[i][j][r];
      } else if (nb < 40) {
        int colg = (nb - 32) * 128 + cl;
#pragma unroll
        for (int r = 0; r < 4; ++r)
          Kb[(size_t)(row0 + r) * 1024 + colg] = (__bf16)acc[i][j][r];
      } else {
        int colg = (nb - 40) * 128 + cl;
        bf16_4 pv = { (__bf16)acc[i][j][0], (__bf16)acc[i][j][1],
                      (__bf16)acc[i][j][2], (__bf16)acc[i][j][3] };
        *(bf16_4*)&Vt[(size_t)colg * S_ + row0] = pv;  // transposed store
      }
    }
  }
}

// ---------- output-projection GEMM: out(fp32) = Ob @ wo^T (m97 128x128) ----------
__global__ __launch_bounds__(256) void gemm_out(const __bf16* __restrict__ Ob,
                                                const __bf16* __restrict__ wob,
                                                float* __restrict__ Of) {
  __shared__ __bf16 As[128 * 32];
  __shared__ __bf16 Bs[128 * 32];
  const int nb = blockIdx.x, mb = blockIdx.y;
  const int tid = threadIdx.x, lane = tid & 63, wv = tid >> 6;
  const int wm = wv >> 1, wn = wv & 1;
  const int srow = lane >> 2, scol = (lane & 3) * 8;

  const __bf16* Ag0 = Ob  + (size_t)(mb * 128 + 2 * wv * 16 + srow) * D_ + scol;
  const __bf16* Bg0 = wob + (size_t)(nb * 128 + 2 * wv * 16 + srow) * D_ + scol;
  __bf16* Al = As + 2 * wv * 512;
  __bf16* Bl = Bs + 2 * wv * 512;

  const f32x4 zv = {0.f, 0.f, 0.f, 0.f};
  f32x4 acc[4][4];
#pragma unroll
  for (int i = 0; i < 4; ++i)
#pragma unroll
    for (int j = 0; j < 4; ++j) acc[i][j] = zv;

  for (int k0 = 0; k0 < D_; k0 += 32) {
    gload_lds16(Ag0 + k0, Al);
    gload_lds16(Ag0 + (size_t)16 * D_ + k0, Al + 512);
    gload_lds16(Bg0 + k0, Bl);
    gload_lds16(Bg0 + (size_t)16 * D_ + k0, Bl + 512);
    __syncthreads();
    bf16_8 af[4], bfr[4];
#pragma unroll
    for (int i = 0; i < 4; ++i)
      af[i] = *(const bf16_8*)&As[(wm * 64 + i * 16 + (lane & 15)) * 32 + (lane >> 4) * 8];
#pragma unroll
    for (int j = 0; j < 4; ++j)
      bfr[j] = *(const bf16_8*)&Bs[(wn * 64 + j * 16 + (lane & 15)) * 32 + (lane >> 4) * 8];
#pragma unroll
    for (int i = 0; i < 4; ++i)
#pragma unroll
      for (int j = 0; j < 4; ++j)
        acc[i][j] = __builtin_amdgcn_mfma_f32_16x16x32_bf16(af[i], bfr[j], acc[i][j], 0, 0, 0);
    __syncthreads();
  }

#pragma unroll
  for (int i = 0; i < 4; ++i) {
    int row0 = mb * 128 + wm * 64 + i * 16 + (lane >> 4) * 4;
#pragma unroll
    for (int j = 0; j < 4; ++j) {
      int colg = nb * 128 + wn * 64 + j * 16 + (lane & 15);
#pragma unroll
      for (int r = 0; r < 4; ++r)
        Of[(size_t)(row0 + r) * D_ + colg] = acc[i][j][r];
    }
  }
}

// ---------- flash attention (causal, GQA), paired-triangle, SWAPPED QK^T, KVB=128 ----------
// grid: x = 16 q-tile pairs (qlo=x, qhi=31-x, 64 q-rows each), y = 32 heads.
// 4 waves x 16 q-rows per tile; each tile-computation covers 128 KV positions.
// mfma(K,Q) -> S^T: lane holds S-values for q = lane&15 (reduction lane-local).
// Tiles per block: ceil((qhi+1)/2) + ceil((qlo+1)/2) = 17 for all x (uniform).
// Mask only on the last tile of each q-tile (proved: earlier tiles end < QB0).
#define COMPUTE_TILE(ACC, MR, LR, AQ, QB0, DOMASK)                                 \
  {                                                                                \
    f32x4 sfr_[8];                                                                 \
    __builtin_amdgcn_s_setprio(1);                                                 \
    _Pragma("unroll")                                                              \
    for (int nf = 0; nf < 8; ++nf) {                                               \
      f32x4 c_ = zv;                                                               \
      _Pragma("unroll")                                                            \
      for (int ks = 0; ks < 4; ++ks) {                                             \
        int n_ = nf * 16 + (lane & 15);                                            \
        int bo_ = (n_ * 256 + (ks * 32 + (lane >> 4) * 8) * 2) ^ ((n_ & 7) << 4);  \
        bf16_8 bk_ = *(const bf16_8*)((char*)Ks + bo_);                            \
        c_ = __builtin_amdgcn_mfma_f32_16x16x32_bf16(bk_, AQ[ks], c_, 0, 0, 0);    \
      }                                                                            \
      sfr_[nf] = c_;                                                               \
    }                                                                              \
    __builtin_amdgcn_s_setprio(0);                                                 \
    const int myq_ = (QB0) + w * 16 + (lane & 15);                                 \
    float pm_ = -3e38f;                                                            \
    _Pragma("unroll")                                                              \
    for (int nf = 0; nf < 8; ++nf) {                                               \
      _Pragma("unroll")                                                            \
      for (int r = 0; r < 4; ++r) {                                                \
        int kcol_ = kb * 128 + nf * 16 + (lane >> 4) * 4 + r;                      \
        float v_ = sfr_[nf][r] * sc;                                               \
        if ((DOMASK) && kcol_ > myq_) v_ = -1e9f;                                  \
        sfr_[nf][r] = v_;                                                          \
        pm_ = fmaxf(pm_, v_);                                                      \
      }                                                                            \
    }                                                                              \
    pm_ = fmaxf(pm_, __shfl_xor(pm_, 16));                                         \
    pm_ = fmaxf(pm_, __shfl_xor(pm_, 32));                                         \
    if (!__all(pm_ <= MR + 8.f)) {                                                 \
      float mn_ = fmaxf(MR, pm_);                                                  \
      float rs_ = __expf(MR - mn_);                                                \
      MR = mn_;                                                                    \
      LR *= rs_;                                                                   \
      float rsb_[4];                                                               \
      _Pragma("unroll")                                                            \
      for (int r = 0; r < 4; ++r)                                                  \
        rsb_[r] = __shfl(rs_, (lane & 48) | ((lane >> 4) * 4 + r));                \
      _Pragma("unroll")                                                            \
      for (int d = 0; d < 8; ++d)                                                  \
        _Pragma("unroll")                                                          \
        for (int r = 0; r < 4; ++r) ACC[d][r] *= rsb_[r];                          \
    }                                                                              \
    float ps_ = 0.f;                                                               \
    _Pragma("unroll")                                                              \
    for (int nf = 0; nf < 8; ++nf) {                                               \
      bf16_4 pk_;                                                                  \
      _Pragma("unroll")                                                            \
      for (int r = 0; r < 4; ++r) {                                                \
        float p_ = __expf(sfr_[nf][r] - MR);                                       \
        ps_ += p_;                                                                 \
        pk_[r] = (__bf16)p_;                                                       \
      }                                                                            \
      int bo_ = ((lane & 15) * 256 + nf * 32 + (lane >> 4) * 8) ^                  \
                (((lane & 15) & 7) << 4);                                          \
      *(bf16_4*)((char*)(&Ps[w][0]) + bo_) = pk_;                                  \
    }                                                                              \
    ps_ += __shfl_xor(ps_, 16);                                                    \
    ps_ += __shfl_xor(ps_, 32);                                                    \
    LR += ps_;                                                                     \
    bf16_8 ap_[4];                                                                 \
    _Pragma("unroll")                                                              \
    for (int ks = 0; ks < 4; ++ks) {                                               \
      int bo_ = ((lane & 15) * 256 + (ks * 32 + (lane >> 4) * 8) * 2) ^            \
                (((lane & 15) & 7) << 4);                                          \
      ap_[ks] = *(const bf16_8*)((char*)(&Ps[w][0]) + bo_);                        \
    }                                                                              \
    __builtin_amdgcn_s_setprio(1);                                                 \
    _Pragma("unroll")                                                              \
    for (int d = 0; d < 8; ++d) {                                                  \
      _Pragma("unroll")                                                            \
      for (int ks = 0; ks < 4; ++ks) {                                             \
        int dr_ = d * 16 + (lane & 15);                                            \
        int bo_ = (dr_ * 256 + (ks * 32 + (lane >> 4) * 8) * 2) ^ ((dr_ & 7) << 4);\
        bf16_8 bv_ = *(const bf16_8*)((char*)Vs + bo_);                            \
        ACC[d] = __builtin_amdgcn_mfma_f32_16x16x32_bf16(ap_[ks], bv_, ACC[d], 0, 0, 0); \
      }                                                                            \
    }                                                                              \
    __builtin_amdgcn_s_setprio(0);                                                 \
  }

__global__ __launch_bounds__(256, 2) void attn_k(const __bf16* __restrict__ Qb,
                                                 const __bf16* __restrict__ Kb,
                                                 const __bf16* __restrict__ Vt,
                                                 __bf16* __restrict__ Ob) {
  __shared__ __bf16 Ks[128 * 128];     // K[pos][d], row stride 256B, swizzled (32 KB)
  __shared__ __bf16 Vs[128 * 128];     // V^T[d][pos], row stride 256B, swizzled (32 KB)
  __shared__ __bf16 Ps[4][16 * 128];   // per-wave P[q][k], row stride 256B, swizzled (16 KB)
  const int x = blockIdx.x, h = blockIdx.y, kvh = h >> 2;
  const int qlo = x, qhi = 31 - x;
  const int Tlo = (qlo >> 1) + 1, Thi = (qhi >> 1) + 1;
  const int tid = threadIdx.x, lane = tid & 63, w = tid >> 6;

  // Q fragments straight from global (once per block, both tiles)
  bf16_8 aq0[4], aq1[4];
#pragma unroll
  for (int ks = 0; ks < 4; ++ks) {
    int rr = w * 16 + (lane & 15);
    int cc = h * 128 + ks * 32 + (lane >> 4) * 8;
    aq0[ks] = *(const bf16_8*)&Qb[(size_t)(qlo * 64 + rr) * D_ + cc];
    aq1[ks] = *(const bf16_8*)&Qb[(size_t)(qhi * 64 + rr) * D_ + cc];
  }

  const f32x4 zv = {0.f, 0.f, 0.f, 0.f};
  f32x4 accO0[8], accO1[8];
#pragma unroll
  for (int d = 0; d < 8; ++d) { accO0[d] = zv; accO1[d] = zv; }
  float mr0 = -3e38f, lr0 = 0.f, mr1 = -3e38f, lr1 = 0.f;

  const float sc = 0.08838834764831845f;  // 1/sqrt(128)

  // staging registers (async-split: global load early, LDS-write after barrier)
  bf16_8 rK[8], rV[8];
#define KLOAD(KB)                                                                  \
  {                                                                                \
    _Pragma("unroll")                                                              \
    for (int u = 0; u < 8; ++u) {                                                  \
      int cid = u * 256 + tid; int row = cid >> 4, c8 = cid & 15;                  \
      rK[u] = *(const bf16_8*)&Kb[(size_t)((KB) * 128 + row) * 1024 + kvh * 128 + c8 * 8]; \
    }                                                                              \
    _Pragma("unroll")                                                              \
    for (int u = 0; u < 8; ++u) {                                                  \
      int cid = u * 256 + tid; int vr = cid >> 4, c8 = cid & 15;                   \
      rV[u] = *(const bf16_8*)&Vt[(size_t)(kvh * 128 + vr) * S_ + (KB) * 128 + c8 * 8]; \
    }                                                                              \
  }
#define KSTORE()                                                                   \
  {                                                                                \
    _Pragma("unroll")                                                              \
    for (int u = 0; u < 8; ++u) {                                                  \
      int cid = u * 256 + tid; int row = cid >> 4, c8 = cid & 15;                  \
      int bo = (row * 256 + c8 * 16) ^ ((row & 7) << 4);                           \
      *(bf16_8*)((char*)Ks + bo) = rK[u];                                          \
    }                                                                              \
    _Pragma("unroll")                                                              \
    for (int u = 0; u < 8; ++u) {                                                  \
      int cid = u * 256 + tid; int vr = cid >> 4, c8 = cid & 15;                   \
      int bo = (vr * 256 + c8 * 16) ^ ((vr & 7) << 4);                             \
      *(bf16_8*)((char*)Vs + bo) = rV[u];                                          \
    }                                                                              \
  }

  KLOAD(0);
  KSTORE();
  __syncthreads();

  for (int kb = 0; kb < Thi; ++kb) {
    if (kb + 1 < Thi) KLOAD(kb + 1);  // in flight during compute
    COMPUTE_TILE(accO1, mr1, lr1, aq1, qhi * 64, (kb == Thi - 1));
    if (kb < Tlo) COMPUTE_TILE(accO0, mr0, lr0, aq0, qlo * 64, (kb == Tlo - 1));
    if (kb + 1 < Thi) {
      __syncthreads();   // everyone done reading Ks/Vs
      KSTORE();          // vmcnt wait on rK/rV handled by compiler
      __syncthreads();   // next tile ready
    }
  }

  // normalize + store both tiles (l lives at lane q = lane&15 -> shuffle per row)
  float inv0[4], inv1[4];
#pragma unroll
  for (int r = 0; r < 4; ++r) {
    int src = (lane & 48) | ((lane >> 4) * 4 + r);
    inv0[r] = 1.0f / __shfl(lr0, src);
    inv1[r] = 1.0f / __shfl(lr1, src);
  }
#pragma unroll
  for (int d = 0; d < 8; ++d) {
#pragma unroll
    for (int r = 0; r < 4; ++r) {
      size_t rl = (size_t)(qlo * 64 + w * 16 + (lane >> 4) * 4 + r);
      size_t rh = (size_t)(qhi * 64 + w * 16 + (lane >> 4) * 4 + r);
      int cc = h * 128 + d * 16 + (lane & 15);
      Ob[rl * D_ + cc] = (__bf16)(accO0[d][r] * inv0[r]);
      Ob[rh * D_ + cc] = (__bf16)(accO1[d][r] * inv1[r]);
    }
  }
}

// ---------- launch ----------
extern "C" void kernel_launch(void* const* d_in, const int* in_sizes, int n_in,
                              void* d_out, int out_size, void* d_ws, size_t ws_size,
                              hipStream_t stream) {
  const float* x    = (const float*)d_in[0];
  const float* wq   = (const float*)d_in[1];
  const float* wk   = (const float*)d_in[2];
  const float* wv   = (const float*)d_in[3];
  const float* wo   = (const float*)d_in[4];
  const float* cosT = (const float*)d_in[5];
  const float* sinT = (const float*)d_in[6];
  float* out = (float*)d_out;
  char* ws = (char*)d_ws;

  __bf16* xb  = (__bf16*)(ws + 0);            // 2048x4096; later reused as Ob
  __bf16* wqb = (__bf16*)(ws + 16777216);     // 4096x4096
  __bf16* wkb = (__bf16*)(ws + 50331648);     // 1024x4096
  __bf16* wvb = (__bf16*)(ws + 58720256);     // 1024x4096
  __bf16* wob = (__bf16*)(ws + 67108864);     // 4096x4096
  __bf16* Qb  = (__bf16*)(ws + 100663296);    // 2048x4096
  __bf16* Kb  = (__bf16*)(ws + 117440512);    // 2048x1024
  __bf16* Vt  = (__bf16*)(ws + 121634816);    // 1024x2048 (V transposed)
  __bf16* Ob  = xb;                           // alias: x consumed before attention writes

  // fused fp32 -> bf16 (dst = xb..wob contiguous)
  cvt_all<<<49152, 256, 0, stream>>>(x, wq, wk, wv, wo, xb);

  // fused QKV projection, m97 128x128 structure (V stored transposed)
  gemm_qkv<<<dim3(48, 16), 256, 0, stream>>>(xb, wqb, wkb, wvb, Qb, Kb, Vt);

  // RoPE on Q and K (in place)
  rope_k<<<5120, 256, 0, stream>>>(Qb, Kb, cosT, sinT);

  // causal GQA flash attention (paired triangle, swapped QK^T, KVB=128)
  attn_k<<<dim3(16, 32), 256, 0, stream>>>(Qb, Kb, Vt, Ob);

  // output projection -> fp32
  gemm_out<<<dim3(32, 16), 256, 0, stream>>>(Ob, wob, out);
}

// Round 7
// 391.702 us; speedup vs baseline: 1.3107x; 1.3107x over previous
//
#include <hip/hip_runtime.h>
#include <stdint.h>

// ---------- types ----------
typedef __bf16 bf16_8 __attribute__((ext_vector_type(8)));
typedef __bf16 bf16_4 __attribute__((ext_vector_type(4)));
typedef float  f32x4  __attribute__((ext_vector_type(4)));

#define B_  1
#define S_  2048
#define D_  4096
#define H_  32
#define KV_ 8
#define HD_ 128

__device__ inline void gload_lds16(const void* g, void* l) {
  __builtin_amdgcn_global_load_lds((const __attribute__((address_space(1))) void*)g,
                                   (__attribute__((address_space(3))) void*)l, 16, 0, 0);
}

// ---------- fused fp32 -> bf16 convert (all 5 tensors; dst contiguous in ws) ----------
__global__ __launch_bounds__(256) void cvt_all(const float* __restrict__ x,
                                               const float* __restrict__ wq,
                                               const float* __restrict__ wk,
                                               const float* __restrict__ wv,
                                               const float* __restrict__ wo,
                                               __bf16* __restrict__ dst) {
  int i = blockIdx.x * 256 + threadIdx.x;  // float4-chunk index, total 12,582,912
  const float* s;
  int j = i;
  if (j < 2097152) s = x;
  else if ((j -= 2097152) < 4194304) s = wq;
  else if ((j -= 4194304) < 1048576) s = wk;
  else if ((j -= 1048576) < 1048576) s = wv;
  else { j -= 1048576; s = wo; }
  float4 v = ((const float4*)s)[j];
  bf16_4 o = { (__bf16)v.x, (__bf16)v.y, (__bf16)v.z, (__bf16)v.w };
  ((bf16_4*)dst)[i] = o;
}

// ---------- RoPE (in-place on bf16 Q and K) ----------
__global__ __launch_bounds__(256) void rope_k(__bf16* __restrict__ Qb, __bf16* __restrict__ Kb,
                                              const float* __restrict__ cosT,
                                              const float* __restrict__ sinT) {
  int t = blockIdx.x * 256 + threadIdx.x;
  const int NQ = S_ * (D_ / 8);
  __bf16* p;
  int row, cl8;
  if (t < NQ) { row = t >> 9; cl8 = t & 511; p = Qb + (size_t)row * D_ + cl8 * 8; }
  else        { int u = t - NQ; row = u >> 7; cl8 = u & 127; p = Kb + (size_t)row * 1024 + cl8 * 8; }
  bf16_8 v = *(bf16_8*)p;
  int fi0 = ((cl8 * 8) & 127) >> 1;
  float4 c4 = *(const float4*)&cosT[row * 64 + fi0];
  float4 s4 = *(const float4*)&sinT[row * 64 + fi0];
  float cc[4] = {c4.x, c4.y, c4.z, c4.w};
  float ss[4] = {s4.x, s4.y, s4.z, s4.w};
  bf16_8 o;
#pragma unroll
  for (int j = 0; j < 4; ++j) {
    float xr = (float)v[2 * j], xi = (float)v[2 * j + 1];
    o[2 * j]     = (__bf16)(xr * cc[j] - xi * ss[j]);
    o[2 * j + 1] = (__bf16)(xr * ss[j] + xi * cc[j]);
  }
  *(bf16_8*)p = o;
}

// ---------- fused QKV GEMM (m97-style 128x128 tile, BK=32) ----------
__global__ __launch_bounds__(256) void gemm_qkv(const __bf16* __restrict__ xb,
                                                const __bf16* __restrict__ wqb,
                                                const __bf16* __restrict__ wkb,
                                                const __bf16* __restrict__ wvb,
                                                __bf16* __restrict__ Qb,
                                                __bf16* __restrict__ Kb,
                                                __bf16* __restrict__ Vt) {
  __shared__ __bf16 As[128 * 32];
  __shared__ __bf16 Bs[128 * 32];
  const int nb = blockIdx.x, mb = blockIdx.y;
  const __bf16* W; int wrow0;
  if (nb < 32)      { W = wqb; wrow0 = nb * 128; }
  else if (nb < 40) { W = wkb; wrow0 = (nb - 32) * 128; }
  else              { W = wvb; wrow0 = (nb - 40) * 128; }
  const int tid = threadIdx.x, lane = tid & 63, wv = tid >> 6;
  const int wm = wv >> 1, wn = wv & 1;
  const int srow = lane >> 2, scol = (lane & 3) * 8;

  const __bf16* Ag0 = xb + (size_t)(mb * 128 + 2 * wv * 16 + srow) * D_ + scol;
  const __bf16* Bg0 = W  + (size_t)(wrow0 + 2 * wv * 16 + srow) * D_ + scol;
  __bf16* Al = As + 2 * wv * 512;
  __bf16* Bl = Bs + 2 * wv * 512;

  const f32x4 zv = {0.f, 0.f, 0.f, 0.f};
  f32x4 acc[4][4];
#pragma unroll
  for (int i = 0; i < 4; ++i)
#pragma unroll
    for (int j = 0; j < 4; ++j) acc[i][j] = zv;

  for (int k0 = 0; k0 < D_; k0 += 32) {
    gload_lds16(Ag0 + k0, Al);
    gload_lds16(Ag0 + (size_t)16 * D_ + k0, Al + 512);
    gload_lds16(Bg0 + k0, Bl);
    gload_lds16(Bg0 + (size_t)16 * D_ + k0, Bl + 512);
    __syncthreads();
    bf16_8 af[4], bfr[4];
#pragma unroll
    for (int i = 0; i < 4; ++i)
      af[i] = *(const bf16_8*)&As[(wm * 64 + i * 16 + (lane & 15)) * 32 + (lane >> 4) * 8];
#pragma unroll
    for (int j = 0; j < 4; ++j)
      bfr[j] = *(const bf16_8*)&Bs[(wn * 64 + j * 16 + (lane & 15)) * 32 + (lane >> 4) * 8];
#pragma unroll
    for (int i = 0; i < 4; ++i)
#pragma unroll
      for (int j = 0; j < 4; ++j)
        acc[i][j] = __builtin_amdgcn_mfma_f32_16x16x32_bf16(af[i], bfr[j], acc[i][j], 0, 0, 0);
    __syncthreads();
  }

#pragma unroll
  for (int i = 0; i < 4; ++i) {
    int row0 = mb * 128 + wm * 64 + i * 16 + (lane >> 4) * 4;
#pragma unroll
    for (int j = 0; j < 4; ++j) {
      int cl = wn * 64 + j * 16 + (lane & 15);
      if (nb < 32) {
        int colg = nb * 128 + cl;
#pragma unroll
        for (int r = 0; r < 4; ++r)
          Qb[(size_t)(row0 + r) * D_ + colg] = (__bf16)acc[i][j][r];
      } else if (nb < 40) {
        int colg = (nb - 32) * 128 + cl;
#pragma unroll
        for (int r = 0; r < 4; ++r)
          Kb[(size_t)(row0 + r) * 1024 + colg] = (__bf16)acc[i][j][r];
      } else {
        int colg = (nb - 40) * 128 + cl;
        bf16_4 pv = { (__bf16)acc[i][j][0], (__bf16)acc[i][j][1],
                      (__bf16)acc[i][j][2], (__bf16)acc[i][j][3] };
        *(bf16_4*)&Vt[(size_t)colg * S_ + row0] = pv;  // transposed store
      }
    }
  }
}

// ---------- output-projection GEMM: out(fp32) = Ob @ wo^T (m97 128x128) ----------
__global__ __launch_bounds__(256) void gemm_out(const __bf16* __restrict__ Ob,
                                                const __bf16* __restrict__ wob,
                                                float* __restrict__ Of) {
  __shared__ __bf16 As[128 * 32];
  __shared__ __bf16 Bs[128 * 32];
  const int nb = blockIdx.x, mb = blockIdx.y;
  const int tid = threadIdx.x, lane = tid & 63, wv = tid >> 6;
  const int wm = wv >> 1, wn = wv & 1;
  const int srow = lane >> 2, scol = (lane & 3) * 8;

  const __bf16* Ag0 = Ob  + (size_t)(mb * 128 + 2 * wv * 16 + srow) * D_ + scol;
  const __bf16* Bg0 = wob + (size_t)(nb * 128 + 2 * wv * 16 + srow) * D_ + scol;
  __bf16* Al = As + 2 * wv * 512;
  __bf16* Bl = Bs + 2 * wv * 512;

  const f32x4 zv = {0.f, 0.f, 0.f, 0.f};
  f32x4 acc[4][4];
#pragma unroll
  for (int i = 0; i < 4; ++i)
#pragma unroll
    for (int j = 0; j < 4; ++j) acc[i][j] = zv;

  for (int k0 = 0; k0 < D_; k0 += 32) {
    gload_lds16(Ag0 + k0, Al);
    gload_lds16(Ag0 + (size_t)16 * D_ + k0, Al + 512);
    gload_lds16(Bg0 + k0, Bl);
    gload_lds16(Bg0 + (size_t)16 * D_ + k0, Bl + 512);
    __syncthreads();
    bf16_8 af[4], bfr[4];
#pragma unroll
    for (int i = 0; i < 4; ++i)
      af[i] = *(const bf16_8*)&As[(wm * 64 + i * 16 + (lane & 15)) * 32 + (lane >> 4) * 8];
#pragma unroll
    for (int j = 0; j < 4; ++j)
      bfr[j] = *(const bf16_8*)&Bs[(wn * 64 + j * 16 + (lane & 15)) * 32 + (lane >> 4) * 8];
#pragma unroll
    for (int i = 0; i < 4; ++i)
#pragma unroll
      for (int j = 0; j < 4; ++j)
        acc[i][j] = __builtin_amdgcn_mfma_f32_16x16x32_bf16(af[i], bfr[j], acc[i][j], 0, 0, 0);
    __syncthreads();
  }

#pragma unroll
  for (int i = 0; i < 4; ++i) {
    int row0 = mb * 128 + wm * 64 + i * 16 + (lane >> 4) * 4;
#pragma unroll
    for (int j = 0; j < 4; ++j) {
      int colg = nb * 128 + wn * 64 + j * 16 + (lane & 15);
#pragma unroll
      for (int r = 0; r < 4; ++r)
        Of[(size_t)(row0 + r) * D_ + colg] = acc[i][j][r];
    }
  }
}

// ---------- flash attention (causal, GQA), paired-triangle, SWAPPED QK^T, KVB=64 ----------
// grid: x = 16 q-tile pairs (qlo=x, qhi=31-x), y = 32 heads. 4 waves x 16 q-rows/tile.
// mfma(K,Q) -> S^T: lane holds 16 S-values for q = lane&15 (reduction lane-local).
// Staging: global_load_lds with PRE-SWIZZLED global source (linear LDS dest,
// source chunk c8 ^= row&7; read-side XOR unchanged) -- no staging VGPRs, 1 barrier/tile.
// Q fragments pre-scaled by 1/sqrt(HD) at load (S arrives pre-scaled from MFMA).
#define COMPUTE_TILE(ACC, MR, LR, AQ, QB0, DOMASK, KSB, VSB)                       \
  {                                                                                \
    f32x4 sfr_[4];                                                                 \
    __builtin_amdgcn_s_setprio(1);                                                 \
    _Pragma("unroll")                                                              \
    for (int nf = 0; nf < 4; ++nf) {                                               \
      f32x4 c_ = zv;                                                               \
      _Pragma("unroll")                                                            \
      for (int ks = 0; ks < 4; ++ks) {                                             \
        int n_ = nf * 16 + (lane & 15);                                            \
        int bo_ = (n_ * 256 + (ks * 32 + (lane >> 4) * 8) * 2) ^ ((n_ & 7) << 4);  \
        bf16_8 bk_ = *(const bf16_8*)((char*)(KSB) + bo_);                         \
        c_ = __builtin_amdgcn_mfma_f32_16x16x32_bf16(bk_, AQ[ks], c_, 0, 0, 0);    \
      }                                                                            \
      sfr_[nf] = c_;                                                               \
    }                                                                              \
    __builtin_amdgcn_s_setprio(0);                                                 \
    const int myq_ = (QB0) + w * 16 + (lane & 15);                                 \
    float pmn_[4];                                                                 \
    _Pragma("unroll")                                                              \
    for (int nf = 0; nf < 4; ++nf) {                                               \
      float t_ = -3e38f;                                                           \
      _Pragma("unroll")                                                            \
      for (int r = 0; r < 4; ++r) {                                                \
        int kcol_ = kb * 64 + nf * 16 + (lane >> 4) * 4 + r;                       \
        float v_ = sfr_[nf][r];                                                    \
        if ((DOMASK) && kcol_ > myq_) v_ = -1e9f;                                  \
        sfr_[nf][r] = v_;                                                          \
        t_ = fmaxf(t_, v_);                                                        \
      }                                                                            \
      pmn_[nf] = t_;                                                               \
    }                                                                              \
    float pm_ = fmaxf(fmaxf(pmn_[0], pmn_[1]), fmaxf(pmn_[2], pmn_[3]));           \
    pm_ = fmaxf(pm_, __shfl_xor(pm_, 16));                                         \
    pm_ = fmaxf(pm_, __shfl_xor(pm_, 32));                                         \
    if (!__all(pm_ <= MR + 8.f)) {                                                 \
      float mn_ = fmaxf(MR, pm_);                                                  \
      float rs_ = __expf(MR - mn_);                                                \
      MR = mn_;                                                                    \
      LR *= rs_;                                                                   \
      float rsb_[4];                                                               \
      _Pragma("unroll")                                                            \
      for (int r = 0; r < 4; ++r)                                                  \
        rsb_[r] = __shfl(rs_, (lane & 48) | ((lane >> 4) * 4 + r));                \
      _Pragma("unroll")                                                            \
      for (int d = 0; d < 8; ++d)                                                  \
        _Pragma("unroll")                                                          \
        for (int r = 0; r < 4; ++r) ACC[d][r] *= rsb_[r];                          \
    }                                                                              \
    float psn_[4];                                                                 \
    _Pragma("unroll")                                                              \
    for (int nf = 0; nf < 4; ++nf) {                                               \
      bf16_4 pk_;                                                                  \
      float t_ = 0.f;                                                              \
      _Pragma("unroll")                                                            \
      for (int r = 0; r < 4; ++r) {                                                \
        float p_ = __expf(sfr_[nf][r] - MR);                                       \
        t_ += p_;                                                                  \
        pk_[r] = (__bf16)p_;                                                       \
      }                                                                            \
      psn_[nf] = t_;                                                               \
      int bo_ = ((lane & 15) * 128 + nf * 32 + (lane >> 4) * 8) ^                  \
                (((lane & 15) & 7) << 4);                                          \
      *(bf16_4*)((char*)(&Ps[w][0]) + bo_) = pk_;                                  \
    }                                                                              \
    float ps_ = (psn_[0] + psn_[1]) + (psn_[2] + psn_[3]);                         \
    ps_ += __shfl_xor(ps_, 16);                                                    \
    ps_ += __shfl_xor(ps_, 32);                                                    \
    LR += ps_;                                                                     \
    bf16_8 ap_[2];                                                                 \
    _Pragma("unroll")                                                              \
    for (int ks = 0; ks < 2; ++ks) {                                               \
      int bo_ = ((lane & 15) * 128 + (ks * 32 + (lane >> 4) * 8) * 2) ^            \
                (((lane & 15) & 7) << 4);                                          \
      ap_[ks] = *(const bf16_8*)((char*)(&Ps[w][0]) + bo_);                        \
    }                                                                              \
    __builtin_amdgcn_s_setprio(1);                                                 \
    _Pragma("unroll")                                                              \
    for (int d = 0; d < 8; ++d) {                                                  \
      _Pragma("unroll")                                                            \
      for (int ks = 0; ks < 2; ++ks) {                                             \
        int dr_ = d * 16 + (lane & 15);                                            \
        int bo_ = (dr_ * 128 + (ks * 32 + (lane >> 4) * 8) * 2) ^ ((dr_ & 7) << 4);\
        bf16_8 bv_ = *(const bf16_8*)((char*)(VSB) + bo_);                         \
        ACC[d] = __builtin_amdgcn_mfma_f32_16x16x32_bf16(ap_[ks], bv_, ACC[d], 0, 0, 0); \
      }                                                                            \
    }                                                                              \
    __builtin_amdgcn_s_setprio(0);                                                 \
  }

__global__ __launch_bounds__(256) void attn_k(const __bf16* __restrict__ Qb,
                                              const __bf16* __restrict__ Kb,
                                              const __bf16* __restrict__ Vt,
                                              __bf16* __restrict__ Ob) {
  __shared__ __bf16 Ks[2][64 * 128];   // K[pos][d], row 256B, phys chunk c8 = logical c8^(row&7)
  __shared__ __bf16 Vs[2][128 * 64];   // V^T[d][pos], row 128B, same swizzle convention
  __shared__ __bf16 Ps[4][16 * 64];    // per-wave P[q][k], row 128B, swizzled
  const int x = blockIdx.x, h = blockIdx.y, kvh = h >> 2;
  const int qlo = x, qhi = 31 - x;
  const int tid = threadIdx.x, lane = tid & 63, w = tid >> 6;

  const float sc = 0.08838834764831845f;  // 1/sqrt(128)

  // Q fragments straight from global, pre-scaled by sc
  bf16_8 aq0[4], aq1[4];
#pragma unroll
  for (int ks = 0; ks < 4; ++ks) {
    int rr = w * 16 + (lane & 15);
    int cc = h * 128 + ks * 32 + (lane >> 4) * 8;
    bf16_8 t0 = *(const bf16_8*)&Qb[(size_t)(qlo * 64 + rr) * D_ + cc];
    bf16_8 t1 = *(const bf16_8*)&Qb[(size_t)(qhi * 64 + rr) * D_ + cc];
#pragma unroll
    for (int e = 0; e < 8; ++e) {
      aq0[ks][e] = (__bf16)((float)t0[e] * sc);
      aq1[ks][e] = (__bf16)((float)t1[e] * sc);
    }
  }

  const f32x4 zv = {0.f, 0.f, 0.f, 0.f};
  f32x4 accO0[8], accO1[8];
#pragma unroll
  for (int d = 0; d < 8; ++d) { accO0[d] = zv; accO1[d] = zv; }
  float mr0 = -3e38f, lr0 = 0.f, mr1 = -3e38f, lr1 = 0.f;

  // async stage tile KB into buffer BUF: linear LDS dest, pre-swizzled global source.
  // K tile 64x128 (16 chunks/row), V^T tile 128x64 (8 chunks/row); wave-instr (u,w)
  // covers chunks [(u*4+w)*64, +64), LDS base wave-uniform, HW adds lane*16.
#define KSTAGE(BUF, KB)                                                            \
  {                                                                                \
    _Pragma("unroll")                                                              \
    for (int u = 0; u < 4; ++u) {                                                  \
      int chunk = (u * 4 + w) * 64 + lane;                                         \
      int row = chunk >> 4, p8 = chunk & 15;                                       \
      gload_lds16(&Kb[(size_t)((KB) * 64 + row) * 1024 + kvh * 128 + (p8 ^ (row & 7)) * 8], \
                  &Ks[BUF][(u * 4 + w) * 512]);                                    \
    }                                                                              \
    _Pragma("unroll")                                                              \
    for (int u = 0; u < 4; ++u) {                                                  \
      int chunk = (u * 4 + w) * 64 + lane;                                         \
      int vr = chunk >> 3, p8 = chunk & 7;                                         \
      gload_lds16(&Vt[(size_t)(kvh * 128 + vr) * S_ + (KB) * 64 + (p8 ^ (vr & 7)) * 8], \
                  &Vs[BUF][(u * 4 + w) * 512]);                                    \
    }                                                                              \
  }

  KSTAGE(0, 0);
  asm volatile("s_waitcnt vmcnt(0)" ::: "memory");
  __syncthreads();

  for (int kb = 0; kb <= qhi; ++kb) {
    const int cur = kb & 1;
    if (kb < qhi) KSTAGE(cur ^ 1, kb + 1);  // async into idle buffer
    const __bf16* ksb = &Ks[cur][0];
    const __bf16* vsb = &Vs[cur][0];
    COMPUTE_TILE(accO1, mr1, lr1, aq1, qhi * 64, (kb == qhi), ksb, vsb);
    if (kb <= qlo) COMPUTE_TILE(accO0, mr0, lr0, aq0, qlo * 64, (kb == qlo), ksb, vsb);
    if (kb < qhi) {
      asm volatile("s_waitcnt vmcnt(0)" ::: "memory");  // next buffer complete
      __syncthreads();                                  // all waves done with cur
    }
  }

  // normalize + store both tiles (l lives at lane q = lane&15 -> shuffle per row)
  float inv0[4], inv1[4];
#pragma unroll
  for (int r = 0; r < 4; ++r) {
    int src = (lane & 48) | ((lane >> 4) * 4 + r);
    inv0[r] = 1.0f / __shfl(lr0, src);
    inv1[r] = 1.0f / __shfl(lr1, src);
  }
#pragma unroll
  for (int d = 0; d < 8; ++d) {
#pragma unroll
    for (int r = 0; r < 4; ++r) {
      size_t rl = (size_t)(qlo * 64 + w * 16 + (lane >> 4) * 4 + r);
      size_t rh = (size_t)(qhi * 64 + w * 16 + (lane >> 4) * 4 + r);
      int cc = h * 128 + d * 16 + (lane & 15);
      Ob[rl * D_ + cc] = (__bf16)(accO0[d][r] * inv0[r]);
      Ob[rh * D_ + cc] = (__bf16)(accO1[d][r] * inv1[r]);
    }
  }
}

// ---------- launch ----------
extern "C" void kernel_launch(void* const* d_in, const int* in_sizes, int n_in,
                              void* d_out, int out_size, void* d_ws, size_t ws_size,
                              hipStream_t stream) {
  const float* x    = (const float*)d_in[0];
  const float* wq   = (const float*)d_in[1];
  const float* wk   = (const float*)d_in[2];
  const float* wv   = (const float*)d_in[3];
  const float* wo   = (const float*)d_in[4];
  const float* cosT = (const float*)d_in[5];
  const float* sinT = (const float*)d_in[6];
  float* out = (float*)d_out;
  char* ws = (char*)d_ws;

  __bf16* xb  = (__bf16*)(ws + 0);            // 2048x4096; later reused as Ob
  __bf16* wqb = (__bf16*)(ws + 16777216);     // 4096x4096
  __bf16* wkb = (__bf16*)(ws + 50331648);     // 1024x4096
  __bf16* wvb = (__bf16*)(ws + 58720256);     // 1024x4096
  __bf16* wob = (__bf16*)(ws + 67108864);     // 4096x4096
  __bf16* Qb  = (__bf16*)(ws + 100663296);    // 2048x4096
  __bf16* Kb  = (__bf16*)(ws + 117440512);    // 2048x1024
  __bf16* Vt  = (__bf16*)(ws + 121634816);    // 1024x2048 (V transposed)
  __bf16* Ob  = xb;                           // alias: x consumed before attention writes

  // fused fp32 -> bf16 (dst = xb..wob contiguous)
  cvt_all<<<49152, 256, 0, stream>>>(x, wq, wk, wv, wo, xb);

  // fused QKV projection, m97 128x128 structure (V stored transposed)
  gemm_qkv<<<dim3(48, 16), 256, 0, stream>>>(xb, wqb, wkb, wvb, Qb, Kb, Vt);

  // RoPE on Q and K (in place)
  rope_k<<<5120, 256, 0, stream>>>(Qb, Kb, cosT, sinT);

  // causal GQA flash attention (paired triangle, swapped QK^T, gload_lds staging)
  attn_k<<<dim3(16, 32), 256, 0, stream>>>(Qb, Kb, Vt, Ob);

  // output projection -> fp32
  gemm_out<<<dim3(32, 16), 256, 0, stream>>>(Ob, wob, out);
}

// Round 8
// 382.185 us; speedup vs baseline: 1.3434x; 1.0249x over previous
//
#include <hip/hip_runtime.h>
#include <stdint.h>

// ---------- types ----------
typedef __bf16 bf16_8 __attribute__((ext_vector_type(8)));
typedef __bf16 bf16_4 __attribute__((ext_vector_type(4)));
typedef float  f32x4  __attribute__((ext_vector_type(4)));

#define B_  1
#define S_  2048
#define D_  4096
#define H_  32
#define KV_ 8
#define HD_ 128

__device__ inline void gload_lds16(const void* g, void* l) {
  __builtin_amdgcn_global_load_lds((const __attribute__((address_space(1))) void*)g,
                                   (__attribute__((address_space(3))) void*)l, 16, 0, 0);
}

// ---------- fused fp32 -> bf16 convert (all 5 tensors; dst contiguous in ws) ----------
__global__ __launch_bounds__(256) void cvt_all(const float* __restrict__ x,
                                               const float* __restrict__ wq,
                                               const float* __restrict__ wk,
                                               const float* __restrict__ wv,
                                               const float* __restrict__ wo,
                                               __bf16* __restrict__ dst) {
  int i = blockIdx.x * 256 + threadIdx.x;  // float4-chunk index, total 12,582,912
  const float* s;
  int j = i;
  if (j < 2097152) s = x;
  else if ((j -= 2097152) < 4194304) s = wq;
  else if ((j -= 4194304) < 1048576) s = wk;
  else if ((j -= 1048576) < 1048576) s = wv;
  else { j -= 1048576; s = wo; }
  float4 v = ((const float4*)s)[j];
  bf16_4 o = { (__bf16)v.x, (__bf16)v.y, (__bf16)v.z, (__bf16)v.w };
  ((bf16_4*)dst)[i] = o;
}

// ---------- RoPE (in-place on bf16 Q and K) ----------
__global__ __launch_bounds__(256) void rope_k(__bf16* __restrict__ Qb, __bf16* __restrict__ Kb,
                                              const float* __restrict__ cosT,
                                              const float* __restrict__ sinT) {
  int t = blockIdx.x * 256 + threadIdx.x;
  const int NQ = S_ * (D_ / 8);
  __bf16* p;
  int row, cl8;
  if (t < NQ) { row = t >> 9; cl8 = t & 511; p = Qb + (size_t)row * D_ + cl8 * 8; }
  else        { int u = t - NQ; row = u >> 7; cl8 = u & 127; p = Kb + (size_t)row * 1024 + cl8 * 8; }
  bf16_8 v = *(bf16_8*)p;
  int fi0 = ((cl8 * 8) & 127) >> 1;
  float4 c4 = *(const float4*)&cosT[row * 64 + fi0];
  float4 s4 = *(const float4*)&sinT[row * 64 + fi0];
  float cc[4] = {c4.x, c4.y, c4.z, c4.w};
  float ss[4] = {s4.x, s4.y, s4.z, s4.w};
  bf16_8 o;
#pragma unroll
  for (int j = 0; j < 4; ++j) {
    float xr = (float)v[2 * j], xi = (float)v[2 * j + 1];
    o[2 * j]     = (__bf16)(xr * cc[j] - xi * ss[j]);
    o[2 * j + 1] = (__bf16)(xr * ss[j] + xi * cc[j]);
  }
  *(bf16_8*)p = o;
}

// ---------- fused QKV GEMM: 256x256 tile, BK=64, template 8-phase pipeline ----------
// C[m,n] = sum_k x[m,k]*W[n,k]. Grid: 24 col-blocks (16 Q, 4 K, 4 V) x 8 row-blocks.
// 512 threads = 8 waves (2M x 4N), per-wave output 128x64.
// Tile t lives in buf[t&1]; phase p reads A-quarter p (B read once in ph0 into regs).
// ALL in-loop stages target buf[t&1 ^ 1] -> reads/writes disjoint within a tile.
// Stage plan: ph0 B-half0(t+1), ph1 B-half1, ph2 Q0+Q1, ph3 Q2+Q3.
// Counted vmcnt after MFMA: ph0 vmcnt(4), ph1 vmcnt(5), ph2 vmcnt(6), ph3 vmcnt(3)
// (derived from the issue stream; leaves exactly the not-yet-needed loads in flight).
#define STAGE_A(BF, KT, BAND)                                                      \
  {                                                                                \
    int c_ = wid * 64 + lane;                                                      \
    int cs_ = c_ ^ ((c_ >> 3) & 7);                                                \
    gload_lds16(Ag + (size_t)((BAND) * 64 + (c_ >> 3)) * 4096 + (KT) * 64 + (cs_ & 7) * 8, \
                &Abuf[BF][(BAND) * 4096 + wid * 512]);                             \
  }
#define STAGE_BH(BF, KT, HF)                                                       \
  {                                                                                \
    _Pragma("unroll")                                                              \
    for (int l_ = 2 * (HF); l_ < 2 * (HF) + 2; ++l_) {                             \
      int c_ = l_ * 512 + wid * 64 + lane;                                         \
      int cs_ = c_ ^ ((c_ >> 3) & 7);                                              \
      gload_lds16(Wg + (size_t)(c_ >> 3) * 4096 + (KT) * 64 + (cs_ & 7) * 8,       \
                  &Bbuf[BF][l_ * 4096 + wid * 512]);                               \
    }                                                                              \
  }
#define READ_A(P)                                                                  \
  _Pragma("unroll")                                                                \
  for (int r2 = 0; r2 < 2; ++r2)                                                   \
    _Pragma("unroll")                                                              \
    for (int ks = 0; ks < 2; ++ks) {                                               \
      int row_ = (P) * 64 + wm * 32 + r2 * 16 + (lane & 15);                       \
      int bo_ = (row_ * 128 + (ks * 32 + (lane >> 4) * 8) * 2) ^ ((row_ & 7) << 4);\
      aq[r2][ks] = *(const bf16_8*)(Ab + bo_);                                     \
    }
#define READ_B()                                                                   \
  _Pragma("unroll")                                                                \
  for (int j = 0; j < 4; ++j)                                                      \
    _Pragma("unroll")                                                              \
    for (int ks = 0; ks < 2; ++ks) {                                               \
      int row_ = wn * 64 + j * 16 + (lane & 15);                                   \
      int bo_ = (row_ * 128 + (ks * 32 + (lane >> 4) * 8) * 2) ^ ((row_ & 7) << 4);\
      bq[j][ks] = *(const bf16_8*)(Bb + bo_);                                      \
    }
#define PHASE_MFMA(P)                                                              \
  __builtin_amdgcn_s_setprio(1);                                                   \
  _Pragma("unroll")                                                                \
  for (int r2 = 0; r2 < 2; ++r2)                                                   \
    _Pragma("unroll")                                                              \
    for (int j = 0; j < 4; ++j)                                                    \
      _Pragma("unroll")                                                            \
      for (int ks = 0; ks < 2; ++ks)                                               \
        acc[P][r2][j] =                                                            \
            __builtin_amdgcn_mfma_f32_16x16x32_bf16(aq[r2][ks], bq[j][ks], acc[P][r2][j], 0, 0, 0); \
  __builtin_amdgcn_s_setprio(0);
#define PH_PRE()                                                                   \
  __builtin_amdgcn_s_barrier();                                                    \
  asm volatile("s_waitcnt lgkmcnt(0)" ::: "memory");                               \
  __builtin_amdgcn_sched_barrier(0);
#define PH_POST(N)                                                                 \
  asm volatile("s_waitcnt vmcnt(" #N ")" ::: "memory");                            \
  __builtin_amdgcn_s_barrier();

__global__ __launch_bounds__(512) void gemm8_qkv(const __bf16* __restrict__ xb,
                                                 const __bf16* __restrict__ wqb,
                                                 const __bf16* __restrict__ wkb,
                                                 const __bf16* __restrict__ wvb,
                                                 __bf16* __restrict__ Qb,
                                                 __bf16* __restrict__ Kb,
                                                 __bf16* __restrict__ Vt) {
  __shared__ __bf16 Abuf[2][16384];  // 2 x 256x64
  __shared__ __bf16 Bbuf[2][16384];
  const int nb = blockIdx.x, mb = blockIdx.y;
  const int tid = threadIdx.x, lane = tid & 63, wid = tid >> 6;
  const int wm = wid >> 2, wn = wid & 3;

  const __bf16* Wg;
  if (nb < 16)      Wg = wqb + (size_t)nb * 256 * 4096;
  else if (nb < 20) Wg = wkb + (size_t)(nb - 16) * 256 * 4096;
  else              Wg = wvb + (size_t)(nb - 20) * 256 * 4096;
  const __bf16* Ag = xb + (size_t)mb * 256 * 4096;

  const f32x4 zv = {0.f, 0.f, 0.f, 0.f};
  f32x4 acc[4][2][4];
#pragma unroll
  for (int q = 0; q < 4; ++q)
#pragma unroll
    for (int r2 = 0; r2 < 2; ++r2)
#pragma unroll
      for (int j = 0; j < 4; ++j) acc[q][r2][j] = zv;

  // prologue: tile 0 fully into buf 0 (issue order B0,B1,Q0..Q3 = 8 loads/thread)
  STAGE_BH(0, 0, 0); STAGE_BH(0, 0, 1);
  STAGE_A(0, 0, 0); STAGE_A(0, 0, 1); STAGE_A(0, 0, 2); STAGE_A(0, 0, 3);
  asm volatile("s_waitcnt vmcnt(3)" ::: "memory");  // B0,B1,Q0 landed
  __builtin_amdgcn_s_barrier();

  for (int t = 0; t < 64; ++t) {
    const int cur = t & 1, nxt = cur ^ 1;
    const bool so = (t < 63);
    const char* Ab = (const char*)&Abuf[cur][0];
    const char* Bb = (const char*)&Bbuf[cur][0];
    bf16_8 bq[4][2], aq[2][2];
    // ---- phase 0 ----
    READ_B();
    READ_A(0);
    if (so) { STAGE_BH(nxt, t + 1, 0); }
    PH_PRE();
    PHASE_MFMA(0);
    PH_POST(4);
    // ---- phase 1 ----
    READ_A(1);
    if (so) { STAGE_BH(nxt, t + 1, 1); }
    PH_PRE();
    PHASE_MFMA(1);
    PH_POST(5);
    // ---- phase 2 ----
    READ_A(2);
    if (so) { STAGE_A(nxt, t + 1, 0); STAGE_A(nxt, t + 1, 1); }
    PH_PRE();
    PHASE_MFMA(2);
    PH_POST(6);
    // ---- phase 3 ----
    READ_A(3);
    if (so) { STAGE_A(nxt, t + 1, 2); STAGE_A(nxt, t + 1, 3); }
    PH_PRE();
    PHASE_MFMA(3);
    PH_POST(3);
  }

  // epilogue (R4-verified)
#pragma unroll
  for (int q = 0; q < 4; ++q)
#pragma unroll
    for (int r2 = 0; r2 < 2; ++r2)
#pragma unroll
      for (int j = 0; j < 4; ++j) {
        int rowb = mb * 256 + q * 64 + wm * 32 + r2 * 16 + (lane >> 4) * 4;
        int col = wn * 64 + j * 16 + (lane & 15);
        if (nb < 16) {
          int colg = nb * 256 + col;
#pragma unroll
          for (int r = 0; r < 4; ++r)
            Qb[(size_t)(rowb + r) * D_ + colg] = (__bf16)acc[q][r2][j][r];
        } else if (nb < 20) {
          int colg = (nb - 16) * 256 + col;
#pragma unroll
          for (int r = 0; r < 4; ++r)
            Kb[(size_t)(rowb + r) * 1024 + colg] = (__bf16)acc[q][r2][j][r];
        } else {
          int colg = (nb - 20) * 256 + col;
          bf16_4 pv = { (__bf16)acc[q][r2][j][0], (__bf16)acc[q][r2][j][1],
                        (__bf16)acc[q][r2][j][2], (__bf16)acc[q][r2][j][3] };
          *(bf16_4*)&Vt[(size_t)colg * S_ + rowb] = pv;  // transposed store
        }
      }
}

// ---------- output-projection GEMM: out(fp32) = Ob @ wo^T (m97 128x128) ----------
__global__ __launch_bounds__(256) void gemm_out(const __bf16* __restrict__ Ob,
                                                const __bf16* __restrict__ wob,
                                                float* __restrict__ Of) {
  __shared__ __bf16 As[128 * 32];
  __shared__ __bf16 Bs[128 * 32];
  const int nb = blockIdx.x, mb = blockIdx.y;
  const int tid = threadIdx.x, lane = tid & 63, wv = tid >> 6;
  const int wm = wv >> 1, wn = wv & 1;
  const int srow = lane >> 2, scol = (lane & 3) * 8;

  const __bf16* Ag0 = Ob  + (size_t)(mb * 128 + 2 * wv * 16 + srow) * D_ + scol;
  const __bf16* Bg0 = wob + (size_t)(nb * 128 + 2 * wv * 16 + srow) * D_ + scol;
  __bf16* Al = As + 2 * wv * 512;
  __bf16* Bl = Bs + 2 * wv * 512;

  const f32x4 zv = {0.f, 0.f, 0.f, 0.f};
  f32x4 acc[4][4];
#pragma unroll
  for (int i = 0; i < 4; ++i)
#pragma unroll
    for (int j = 0; j < 4; ++j) acc[i][j] = zv;

  for (int k0 = 0; k0 < D_; k0 += 32) {
    gload_lds16(Ag0 + k0, Al);
    gload_lds16(Ag0 + (size_t)16 * D_ + k0, Al + 512);
    gload_lds16(Bg0 + k0, Bl);
    gload_lds16(Bg0 + (size_t)16 * D_ + k0, Bl + 512);
    __syncthreads();
    bf16_8 af[4], bfr[4];
#pragma unroll
    for (int i = 0; i < 4; ++i)
      af[i] = *(const bf16_8*)&As[(wm * 64 + i * 16 + (lane & 15)) * 32 + (lane >> 4) * 8];
#pragma unroll
    for (int j = 0; j < 4; ++j)
      bfr[j] = *(const bf16_8*)&Bs[(wn * 64 + j * 16 + (lane & 15)) * 32 + (lane >> 4) * 8];
#pragma unroll
    for (int i = 0; i < 4; ++i)
#pragma unroll
      for (int j = 0; j < 4; ++j)
        acc[i][j] = __builtin_amdgcn_mfma_f32_16x16x32_bf16(af[i], bfr[j], acc[i][j], 0, 0, 0);
    __syncthreads();
  }

#pragma unroll
  for (int i = 0; i < 4; ++i) {
    int row0 = mb * 128 + wm * 64 + i * 16 + (lane >> 4) * 4;
#pragma unroll
    for (int j = 0; j < 4; ++j) {
      int colg = nb * 128 + wn * 64 + j * 16 + (lane & 15);
#pragma unroll
      for (int r = 0; r < 4; ++r)
        Of[(size_t)(row0 + r) * D_ + colg] = acc[i][j][r];
    }
  }
}

// ---------- flash attention (causal, GQA), paired-triangle, SWAPPED QK^T, KVB=64 ----------
#define COMPUTE_TILE(ACC, MR, LR, AQ, QB0, DOMASK, KSB, VSB)                       \
  {                                                                                \
    f32x4 sfr_[4];                                                                 \
    __builtin_amdgcn_s_setprio(1);                                                 \
    _Pragma("unroll")                                                              \
    for (int nf = 0; nf < 4; ++nf) {                                               \
      f32x4 c_ = zv;                                                               \
      _Pragma("unroll")                                                            \
      for (int ks = 0; ks < 4; ++ks) {                                             \
        int n_ = nf * 16 + (lane & 15);                                            \
        int bo_ = (n_ * 256 + (ks * 32 + (lane >> 4) * 8) * 2) ^ ((n_ & 7) << 4);  \
        bf16_8 bk_ = *(const bf16_8*)((char*)(KSB) + bo_);                         \
        c_ = __builtin_amdgcn_mfma_f32_16x16x32_bf16(bk_, AQ[ks], c_, 0, 0, 0);    \
      }                                                                            \
      sfr_[nf] = c_;                                                               \
    }                                                                              \
    __builtin_amdgcn_s_setprio(0);                                                 \
    const int myq_ = (QB0) + w * 16 + (lane & 15);                                 \
    float pmn_[4];                                                                 \
    _Pragma("unroll")                                                              \
    for (int nf = 0; nf < 4; ++nf) {                                               \
      float t_ = -3e38f;                                                           \
      _Pragma("unroll")                                                            \
      for (int r = 0; r < 4; ++r) {                                                \
        int kcol_ = kb * 64 + nf * 16 + (lane >> 4) * 4 + r;                       \
        float v_ = sfr_[nf][r];                                                    \
        if ((DOMASK) && kcol_ > myq_) v_ = -1e9f;                                  \
        sfr_[nf][r] = v_;                                                          \
        t_ = fmaxf(t_, v_);                                                        \
      }                                                                            \
      pmn_[nf] = t_;                                                               \
    }                                                                              \
    float pm_ = fmaxf(fmaxf(pmn_[0], pmn_[1]), fmaxf(pmn_[2], pmn_[3]));           \
    pm_ = fmaxf(pm_, __shfl_xor(pm_, 16));                                         \
    pm_ = fmaxf(pm_, __shfl_xor(pm_, 32));                                         \
    if (!__all(pm_ <= MR + 8.f)) {                                                 \
      float mn_ = fmaxf(MR, pm_);                                                  \
      float rs_ = __expf(MR - mn_);                                                \
      MR = mn_;                                                                    \
      LR *= rs_;                                                                   \
      float rsb_[4];                                                               \
      _Pragma("unroll")                                                            \
      for (int r = 0; r < 4; ++r)                                                  \
        rsb_[r] = __shfl(rs_, (lane & 48) | ((lane >> 4) * 4 + r));                \
      _Pragma("unroll")                                                            \
      for (int d = 0; d < 8; ++d)                                                  \
        _Pragma("unroll")                                                          \
        for (int r = 0; r < 4; ++r) ACC[d][r] *= rsb_[r];                          \
    }                                                                              \
    float psn_[4];                                                                 \
    _Pragma("unroll")                                                              \
    for (int nf = 0; nf < 4; ++nf) {                                               \
      bf16_4 pk_;                                                                  \
      float t_ = 0.f;                                                              \
      _Pragma("unroll")                                                            \
      for (int r = 0; r < 4; ++r) {                                                \
        float p_ = __expf(sfr_[nf][r] - MR);                                       \
        t_ += p_;                                                                  \
        pk_[r] = (__bf16)p_;                                                       \
      }                                                                            \
      psn_[nf] = t_;                                                               \
      int bo_ = ((lane & 15) * 128 + nf * 32 + (lane >> 4) * 8) ^                  \
                (((lane & 15) & 7) << 4);                                          \
      *(bf16_4*)((char*)(&Ps[w][0]) + bo_) = pk_;                                  \
    }                                                                              \
    float ps_ = (psn_[0] + psn_[1]) + (psn_[2] + psn_[3]);                         \
    ps_ += __shfl_xor(ps_, 16);                                                    \
    ps_ += __shfl_xor(ps_, 32);                                                    \
    LR += ps_;                                                                     \
    bf16_8 ap_[2];                                                                 \
    _Pragma("unroll")                                                              \
    for (int ks = 0; ks < 2; ++ks) {                                               \
      int bo_ = ((lane & 15) * 128 + (ks * 32 + (lane >> 4) * 8) * 2) ^            \
                (((lane & 15) & 7) << 4);                                          \
      ap_[ks] = *(const bf16_8*)((char*)(&Ps[w][0]) + bo_);                        \
    }                                                                              \
    __builtin_amdgcn_s_setprio(1);                                                 \
    _Pragma("unroll")                                                              \
    for (int d = 0; d < 8; ++d) {                                                  \
      _Pragma("unroll")                                                            \
      for (int ks = 0; ks < 2; ++ks) {                                             \
        int dr_ = d * 16 + (lane & 15);                                            \
        int bo_ = (dr_ * 128 + (ks * 32 + (lane >> 4) * 8) * 2) ^ ((dr_ & 7) << 4);\
        bf16_8 bv_ = *(const bf16_8*)((char*)(VSB) + bo_);                         \
        ACC[d] = __builtin_amdgcn_mfma_f32_16x16x32_bf16(ap_[ks], bv_, ACC[d], 0, 0, 0); \
      }                                                                            \
    }                                                                              \
    __builtin_amdgcn_s_setprio(0);                                                 \
  }

__global__ __launch_bounds__(256) void attn_k(const __bf16* __restrict__ Qb,
                                              const __bf16* __restrict__ Kb,
                                              const __bf16* __restrict__ Vt,
                                              __bf16* __restrict__ Ob) {
  __shared__ __bf16 Ks[2][64 * 128];   // K[pos][d], row 256B, phys chunk c8 = logical c8^(row&7)
  __shared__ __bf16 Vs[2][128 * 64];   // V^T[d][pos], row 128B, same swizzle convention
  __shared__ __bf16 Ps[4][16 * 64];    // per-wave P[q][k], row 128B, swizzled
  const int x = blockIdx.x, h = blockIdx.y, kvh = h >> 2;
  const int qlo = x, qhi = 31 - x;
  const int tid = threadIdx.x, lane = tid & 63, w = tid >> 6;

  const float sc = 0.08838834764831845f;  // 1/sqrt(128)

  bf16_8 aq0[4], aq1[4];
#pragma unroll
  for (int ks = 0; ks < 4; ++ks) {
    int rr = w * 16 + (lane & 15);
    int cc = h * 128 + ks * 32 + (lane >> 4) * 8;
    bf16_8 t0 = *(const bf16_8*)&Qb[(size_t)(qlo * 64 + rr) * D_ + cc];
    bf16_8 t1 = *(const bf16_8*)&Qb[(size_t)(qhi * 64 + rr) * D_ + cc];
#pragma unroll
    for (int e = 0; e < 8; ++e) {
      aq0[ks][e] = (__bf16)((float)t0[e] * sc);
      aq1[ks][e] = (__bf16)((float)t1[e] * sc);
    }
  }

  const f32x4 zv = {0.f, 0.f, 0.f, 0.f};
  f32x4 accO0[8], accO1[8];
#pragma unroll
  for (int d = 0; d < 8; ++d) { accO0[d] = zv; accO1[d] = zv; }
  float mr0 = -3e38f, lr0 = 0.f, mr1 = -3e38f, lr1 = 0.f;

#define KSTAGE(BUF, KB)                                                            \
  {                                                                                \
    _Pragma("unroll")                                                              \
    for (int u = 0; u < 4; ++u) {                                                  \
      int chunk = (u * 4 + w) * 64 + lane;                                         \
      int row = chunk >> 4, p8 = chunk & 15;                                       \
      gload_lds16(&Kb[(size_t)((KB) * 64 + row) * 1024 + kvh * 128 + (p8 ^ (row & 7)) * 8], \
                  &Ks[BUF][(u * 4 + w) * 512]);                                    \
    }                                                                              \
    _Pragma("unroll")                                                              \
    for (int u = 0; u < 4; ++u) {                                                  \
      int chunk = (u * 4 + w) * 64 + lane;                                         \
      int vr = chunk >> 3, p8 = chunk & 7;                                         \
      gload_lds16(&Vt[(size_t)(kvh * 128 + vr) * S_ + (KB) * 64 + (p8 ^ (vr & 7)) * 8], \
                  &Vs[BUF][(u * 4 + w) * 512]);                                    \
    }                                                                              \
  }

  KSTAGE(0, 0);
  asm volatile("s_waitcnt vmcnt(0)" ::: "memory");
  __syncthreads();

  for (int kb = 0; kb <= qhi; ++kb) {
    const int cur = kb & 1;
    if (kb < qhi) KSTAGE(cur ^ 1, kb + 1);  // async into idle buffer
    const __bf16* ksb = &Ks[cur][0];
    const __bf16* vsb = &Vs[cur][0];
    COMPUTE_TILE(accO1, mr1, lr1, aq1, qhi * 64, (kb == qhi), ksb, vsb);
    if (kb <= qlo) COMPUTE_TILE(accO0, mr0, lr0, aq0, qlo * 64, (kb == qlo), ksb, vsb);
    if (kb < qhi) {
      asm volatile("s_waitcnt vmcnt(0)" ::: "memory");
      __syncthreads();
    }
  }

  float inv0[4], inv1[4];
#pragma unroll
  for (int r = 0; r < 4; ++r) {
    int src = (lane & 48) | ((lane >> 4) * 4 + r);
    inv0[r] = 1.0f / __shfl(lr0, src);
    inv1[r] = 1.0f / __shfl(lr1, src);
  }
#pragma unroll
  for (int d = 0; d < 8; ++d) {
#pragma unroll
    for (int r = 0; r < 4; ++r) {
      size_t rl = (size_t)(qlo * 64 + w * 16 + (lane >> 4) * 4 + r);
      size_t rh = (size_t)(qhi * 64 + w * 16 + (lane >> 4) * 4 + r);
      int cc = h * 128 + d * 16 + (lane & 15);
      Ob[rl * D_ + cc] = (__bf16)(accO0[d][r] * inv0[r]);
      Ob[rh * D_ + cc] = (__bf16)(accO1[d][r] * inv1[r]);
    }
  }
}

// ---------- launch ----------
extern "C" void kernel_launch(void* const* d_in, const int* in_sizes, int n_in,
                              void* d_out, int out_size, void* d_ws, size_t ws_size,
                              hipStream_t stream) {
  const float* x    = (const float*)d_in[0];
  const float* wq   = (const float*)d_in[1];
  const float* wk   = (const float*)d_in[2];
  const float* wv   = (const float*)d_in[3];
  const float* wo   = (const float*)d_in[4];
  const float* cosT = (const float*)d_in[5];
  const float* sinT = (const float*)d_in[6];
  float* out = (float*)d_out;
  char* ws = (char*)d_ws;

  __bf16* xb  = (__bf16*)(ws + 0);            // 2048x4096; later reused as Ob
  __bf16* wqb = (__bf16*)(ws + 16777216);     // 4096x4096
  __bf16* wkb = (__bf16*)(ws + 50331648);     // 1024x4096
  __bf16* wvb = (__bf16*)(ws + 58720256);     // 1024x4096
  __bf16* wob = (__bf16*)(ws + 67108864);     // 4096x4096
  __bf16* Qb  = (__bf16*)(ws + 100663296);    // 2048x4096
  __bf16* Kb  = (__bf16*)(ws + 117440512);    // 2048x1024
  __bf16* Vt  = (__bf16*)(ws + 121634816);    // 1024x2048 (V transposed)
  __bf16* Ob  = xb;                           // alias: x consumed before attention writes

  // fused fp32 -> bf16 (dst = xb..wob contiguous)
  cvt_all<<<49152, 256, 0, stream>>>(x, wq, wk, wv, wo, xb);

  // fused QKV projection, 256^2 8-phase template (V stored transposed)
  gemm8_qkv<<<dim3(24, 8), 512, 0, stream>>>(xb, wqb, wkb, wvb, Qb, Kb, Vt);

  // RoPE on Q and K (in place)
  rope_k<<<5120, 256, 0, stream>>>(Qb, Kb, cosT, sinT);

  // causal GQA flash attention (paired triangle, swapped QK^T, gload_lds staging)
  attn_k<<<dim3(16, 32), 256, 0, stream>>>(Qb, Kb, Vt, Ob);

  // output projection -> fp32
  gemm_out<<<dim3(32, 16), 256, 0, stream>>>(Ob, wob, out);
}